// Round 3
// baseline (433.306 us; speedup 1.0000x reference)
//
#include <hip/hip_runtime.h>

// TRF aligner: out[d, t] = sum over seq with s=sourceIdx[seq], 0 <= t-s < N_WIN
// of TRFs[seq, t-s, d]. Gather formulation (no atomics, sorted sourceIdx).
//
// R3 changes vs R2:
//  * float4 loads along d: thread = (d-group 0..31)x(t-subtile 0..3), each
//    thread loads 8 float4 per candidate seq instead of 32 scalar floats.
//    4x fewer VMEM instructions, 1 KB per wave per instruction.
//  * manual double-buffer across the seq loop (bufA/bufB): prefetch seq+1
//    issues before accumulating seq, so waits are partial (vmcnt(8)) instead
//    of vmcnt(0) -> 2x in-flight bytes per wave, latency overlapped.

#define T_TILE  32   // t-values per block; 100000 = 3125 * 32 exactly
#define T_SUB   8    // t-values per thread (4 sub-tiles * 8 = 32)
#define OUT_DIM 128
#define N_WIN   128

__global__ __launch_bounds__(128, 4) void trf_gather_kernel(
    const float* __restrict__ TRFs,      // (nSeq, N_WIN, OUT_DIM)
    const int*   __restrict__ sourceIdx, // (nSeq,) sorted
    int nSeq, int nRealLen,
    float* __restrict__ out)             // (OUT_DIM, nRealLen)
{
    const int tid = threadIdx.x;
    const int dg  = tid & 31;            // d-group: covers d = 4*dg .. 4*dg+3
    const int st  = tid >> 5;            // t-subtile 0..3
    const int t0  = blockIdx.x * T_TILE;
    const int tb  = t0 + st * T_SUB;     // this thread's first t
    if (t0 >= nRealLen) return;

    // lo = first seq with sourceIdx[seq] >= t0 - (N_WIN-1)
    int lo;
    {
        int target = t0 - (N_WIN - 1);
        int a = 0, b = nSeq;
        while (a < b) { int m = (a + b) >> 1; if (sourceIdx[m] < target) a = m + 1; else b = m; }
        lo = a;
    }
    // hi = first seq with sourceIdx[seq] >= t0 + T_TILE
    int hi;
    {
        int target = t0 + T_TILE;
        int a = lo, b = nSeq;
        while (a < b) { int m = (a + b) >> 1; if (sourceIdx[m] < target) a = m + 1; else b = m; }
        hi = a;
    }

    float4 acc[T_SUB];
#pragma unroll
    for (int i = 0; i < T_SUB; ++i) acc[i] = make_float4(0.f, 0.f, 0.f, 0.f);

    const char* tbase = (const char*)TRFs + (size_t)dg * 16;  // + seq*64KB + k*512B

    // 8 unconditional float4 loads for seq (clamped k stays in this seq's row)
    auto prefetch = [&](float4* buf, int seq, int& s_out) {
        int s = sourceIdx[seq];          // wave-uniform -> scalar load
        s_out = s;
        const char* row = tbase + (size_t)seq * (N_WIN * OUT_DIM * 4);
#pragma unroll
        for (int i = 0; i < T_SUB; ++i) {
            int k  = tb + i - s;
            int kc = k < 0 ? 0 : (k > (N_WIN - 1) ? (N_WIN - 1) : k);
            buf[i] = *(const float4*)(row + (size_t)kc * (OUT_DIM * 4));
        }
    };
    auto accum = [&](const float4* buf, int s) {
#pragma unroll
        for (int i = 0; i < T_SUB; ++i) {
            int k = tb + i - s;
            float m = ((unsigned)k < (unsigned)N_WIN) ? 1.0f : 0.0f;
            acc[i].x += m * buf[i].x;
            acc[i].y += m * buf[i].y;
            acc[i].z += m * buf[i].z;
            acc[i].w += m * buf[i].w;
        }
    };

    if (lo < hi) {
        float4 bufA[T_SUB], bufB[T_SUB];
        int sA, sB;
        int q = lo;
        prefetch(bufA, q, sA);
        while (q + 1 < hi) {
            prefetch(bufB, q + 1, sB);
            accum(bufA, sA);
            ++q;
            if (q + 1 < hi) {
                prefetch(bufA, q + 1, sA);
                accum(bufB, sB);
                ++q;
            } else {
                accum(bufB, sB);
                ++q;
            }
        }
        if (q < hi) accum(bufA, sA);   // odd-count tail
    }

    // Store: thread owns out[4*dg .. 4*dg+3][tb .. tb+8) -> 2 float4 per d-row
#pragma unroll
    for (int j = 0; j < 4; ++j) {
        float r[T_SUB];
#pragma unroll
        for (int i = 0; i < T_SUB; ++i) r[i] = ((const float*)&acc[i])[j];
        float* orow = out + (size_t)(4 * dg + j) * nRealLen + tb;
        if (tb + T_SUB <= nRealLen) {
            *(float4*)(orow + 0) = make_float4(r[0], r[1], r[2], r[3]);
            *(float4*)(orow + 4) = make_float4(r[4], r[5], r[6], r[7]);
        } else {
            for (int i = 0; i < T_SUB; ++i)
                if (tb + i < nRealLen) orow[i] = r[i];
        }
    }
}

extern "C" void kernel_launch(void* const* d_in, const int* in_sizes, int n_in,
                              void* d_out, int out_size, void* d_ws, size_t ws_size,
                              hipStream_t stream) {
    const float* TRFs      = (const float*)d_in[0];
    const int*   sourceIdx = (const int*)d_in[1];
    const int    nSeq      = in_sizes[1];
    const int    nRealLen  = out_size / OUT_DIM;   // out is OUT_DIM x nRealLen fp32

    const int nBlocks = (nRealLen + T_TILE - 1) / T_TILE;
    trf_gather_kernel<<<nBlocks, 128, 0, stream>>>(
        TRFs, sourceIdx, nSeq, nRealLen, (float*)d_out);
}